// Round 3
// baseline (596.290 us; speedup 1.0000x reference)
//
#include <hip/hip_runtime.h>

// DenseGrid multi-LOD bilinear interpolation — binned pipeline.
// LODS = 16..2048, FEAT_DIM=4, N=2,000,000. Output [N,32] f32 (128B/point).
//
// Round-2 finding: monolithic kernel is L2-miss-line bound (FETCH 873MB vs
// ~105MB footprint; ~14M 64B miss-lines * ~900cy / 64 MSHR/CU ~= 340us).
// Fix: counting-sort points into 64x64 spatial bins; process LODs 4-7 one
// bin per block so each bin's grid tiles (~22KB) are L2-resident. LODs 4-7
// written together = one full 64B line per point (no write amplification).
// LODs 0-3 (grids <=256KB, L2-resident anyway) stay in original coalesced order.

typedef float    fx4 __attribute__((ext_vector_type(4)));
typedef float    fx2 __attribute__((ext_vector_type(2)));
typedef unsigned ux4 __attribute__((ext_vector_type(4)));

#define NBDIM 64
#define NBINS (NBDIM * NBDIM)

__device__ __forceinline__ fx4 bilerp_one(const float* __restrict__ g, int res,
                                          float px, float py) {
    float rm1 = (float)(res - 1);
    float fx = px * rm1, fy = py * rm1;
    float cmax = rm1 - 1e-5f;
    float xc = fminf(fmaxf(fx, 0.0f), cmax);
    float yc = fminf(fmaxf(fy, 0.0f), cmax);
    int x1 = (int)xc, y1 = (int)yc;              // xc,yc >= 0 -> trunc == floor
    int x2 = min(x1 + 1, res - 1), y2 = min(y1 + 1, res - 1);
    float x1f = (float)x1, y1f = (float)y1, x2f = (float)x2, y2f = (float)y2;
    float w1 = (x2f - fx) * (y2f - fy);
    float w2 = (fx - x1f) * (y2f - fy);
    float w3 = (x2f - fx) * (fy - y1f);
    float w4 = (fx - x1f) * (fy - y1f);
    const fx4* gc = (const fx4*)g;
    fx4 v1 = gc[x1 + y1 * res];
    fx4 v2 = gc[x2 + y1 * res];
    fx4 v3 = gc[x1 + y2 * res];
    fx4 v4 = gc[x2 + y2 * res];
    return w1 * v1 + w2 * v2 + w3 * v3 + w4 * v4;
}

__device__ __forceinline__ int bin_of(float px, float py) {
    int bx = min(max((int)(px * (float)NBDIM), 0), NBDIM - 1);
    int by = min(max((int)(py * (float)NBDIM), 0), NBDIM - 1);
    return by * NBDIM + bx;
}

// ---- Pass A1: histogram -----------------------------------------------------
__global__ __launch_bounds__(256) void hist_kernel(const float* __restrict__ x,
                                                   unsigned* __restrict__ hist,
                                                   int npts) {
    int n = blockIdx.x * 256 + threadIdx.x;
    if (n >= npts) return;
    fx2 p = *(const fx2*)(x + 2 * (size_t)n);
    atomicAdd(&hist[bin_of(p.x, p.y)], 1u);
}

// ---- Pass A2: exclusive scan of 4096 bins (single block) --------------------
__global__ __launch_bounds__(1024) void scan_kernel(const unsigned* __restrict__ hist,
                                                    unsigned* __restrict__ offs,
                                                    unsigned* __restrict__ starts,
                                                    int npts) {
    __shared__ unsigned s[1024];
    int t = threadIdx.x;
    ux4 h = ((const ux4*)hist)[t];               // 4 bins per thread
    unsigned seg = h.x + h.y + h.z + h.w;
    s[t] = seg;
    __syncthreads();
    for (int off = 1; off < 1024; off <<= 1) {   // Hillis-Steele inclusive
        unsigned v = (t >= off) ? s[t - off] : 0u;
        __syncthreads();
        s[t] += v;
        __syncthreads();
    }
    unsigned excl = t ? s[t - 1] : 0u;           // exclusive prefix of segment
    unsigned b0 = excl, b1 = b0 + h.x, b2 = b1 + h.y, b3 = b2 + h.z;
    offs[4 * t + 0] = b0;  starts[4 * t + 0] = b0;
    offs[4 * t + 1] = b1;  starts[4 * t + 1] = b1;
    offs[4 * t + 2] = b2;  starts[4 * t + 2] = b2;
    offs[4 * t + 3] = b3;  starts[4 * t + 3] = b3;
    if (t == 1023) starts[NBINS] = (unsigned)npts;
}

// ---- Pass A3: scatter records into bin order --------------------------------
__global__ __launch_bounds__(256) void scatter_kernel(const float* __restrict__ x,
                                                      unsigned* __restrict__ offs,
                                                      fx4* __restrict__ recs,
                                                      int npts) {
    int n = blockIdx.x * 256 + threadIdx.x;
    if (n >= npts) return;
    fx2 p = *(const fx2*)(x + 2 * (size_t)n);
    unsigned slot = atomicAdd(&offs[bin_of(p.x, p.y)], 1u);
    fx4 r;
    r.x = p.x; r.y = p.y; r.z = __uint_as_float((unsigned)n); r.w = 0.0f;
    __builtin_nontemporal_store(r, &recs[slot]);
}

// ---- Pass C: binned, LODs 4..7 (res 256..2048), one bin per block -----------
__global__ __launch_bounds__(512) void binned_kernel(
    const fx4* __restrict__ recs, const unsigned* __restrict__ starts,
    const float* __restrict__ g4, const float* __restrict__ g5,
    const float* __restrict__ g6, const float* __restrict__ g7,
    float* __restrict__ out) {
    int b = blockIdx.x;
    unsigned s = starts[b], e = starts[b + 1];
    for (unsigned i = s + threadIdx.x; i < e; i += 512) {
        fx4 r = __builtin_nontemporal_load(&recs[i]);
        float px = r.x, py = r.y;
        unsigned n = __float_as_uint(r.z);
        fx4 o4 = bilerp_one(g4,  256, px, py);
        fx4 o5 = bilerp_one(g5,  512, px, py);
        fx4 o6 = bilerp_one(g6, 1024, px, py);
        fx4 o7 = bilerp_one(g7, 2048, px, py);
        fx4* op = (fx4*)out + (size_t)n * 8 + 4;  // byte off n*128+64, 64B line
        __builtin_nontemporal_store(o4, op + 0);
        __builtin_nontemporal_store(o5, op + 1);
        __builtin_nontemporal_store(o6, op + 2);
        __builtin_nontemporal_store(o7, op + 3);
    }
}

// ---- Pass D: LODs 0..3 (res 16..128), original order, coalesced -------------
__global__ __launch_bounds__(256) void lowlod_kernel(
    const float* __restrict__ x,
    const float* __restrict__ g0, const float* __restrict__ g1,
    const float* __restrict__ g2, const float* __restrict__ g3,
    float* __restrict__ out, int npts) {
    int tid = blockIdx.x * 256 + threadIdx.x;
    int n = tid >> 2;
    if (n >= npts) return;
    int l = tid & 3;
    const float* g = (l < 2) ? ((l == 0) ? g0 : g1) : ((l == 2) ? g2 : g3);
    int res = 16 << l;
    fx2 p = *(const fx2*)(x + 2 * (size_t)n);
    fx4 o = bilerp_one(g, res, p.x, p.y);
    __builtin_nontemporal_store(o, (fx4*)out + (size_t)n * 8 + l);
}

// ---- Fallback: proven round-2 monolithic kernel -----------------------------
__global__ __launch_bounds__(256) void densegrid_kernel(
    const float* __restrict__ xin,
    const float* __restrict__ g0, const float* __restrict__ g1,
    const float* __restrict__ g2, const float* __restrict__ g3,
    const float* __restrict__ g4, const float* __restrict__ g5,
    const float* __restrict__ g6, const float* __restrict__ g7,
    float* __restrict__ out, int npts) {
    int tid = blockIdx.x * blockDim.x + threadIdx.x;
    int n = tid >> 3;
    if (n >= npts) return;
    int lod = tid & 7;
    const float* g =
        (lod < 4) ? ((lod < 2) ? ((lod == 0) ? g0 : g1)
                               : ((lod == 2) ? g2 : g3))
                  : ((lod < 6) ? ((lod == 4) ? g4 : g5)
                               : ((lod == 6) ? g6 : g7));
    int res = 16 << lod;
    fx2 p = *(const fx2*)(xin + (size_t)n * 2);
    fx4 o = bilerp_one(g, res, p.x, p.y);
    __builtin_nontemporal_store(o, (fx4*)out + (size_t)n * 8 + lod);
}

extern "C" void kernel_launch(void* const* d_in, const int* in_sizes, int n_in,
                              void* d_out, int out_size, void* d_ws, size_t ws_size,
                              hipStream_t stream) {
    const float* x  = (const float*)d_in[0];
    const float* g0 = (const float*)d_in[1];
    const float* g1 = (const float*)d_in[2];
    const float* g2 = (const float*)d_in[3];
    const float* g3 = (const float*)d_in[4];
    const float* g4 = (const float*)d_in[5];
    const float* g5 = (const float*)d_in[6];
    const float* g6 = (const float*)d_in[7];
    const float* g7 = (const float*)d_in[8];
    float* out = (float*)d_out;
    int npts = in_sizes[0] / 2;

    // d_ws layout: hist @0 (16KB) | offs @16KB (16KB) | starts @32KB (16.4KB)
    //              | records @64KB (npts*16B)
    size_t need = 65536 + (size_t)npts * 16;
    if (ws_size >= need) {
        unsigned* hist   = (unsigned*)d_ws;
        unsigned* offs   = (unsigned*)((char*)d_ws + 16384);
        unsigned* starts = (unsigned*)((char*)d_ws + 32768);
        fx4*      recs   = (fx4*)((char*)d_ws + 65536);

        hipMemsetAsync(hist, 0, NBINS * sizeof(unsigned), stream);

        int gpts = (npts + 255) / 256;
        hist_kernel<<<gpts, 256, 0, stream>>>(x, hist, npts);
        scan_kernel<<<1, 1024, 0, stream>>>(hist, offs, starts, npts);
        scatter_kernel<<<gpts, 256, 0, stream>>>(x, offs, recs, npts);
        binned_kernel<<<NBINS, 512, 0, stream>>>(recs, starts, g4, g5, g6, g7, out);
        int glow = (npts * 4 + 255) / 256;
        lowlod_kernel<<<glow, 256, 0, stream>>>(x, g0, g1, g2, g3, out, npts);
    } else {
        int total = npts * 8;
        densegrid_kernel<<<(total + 255) / 256, 256, 0, stream>>>(
            x, g0, g1, g2, g3, g4, g5, g6, g7, out, npts);
    }
}

// Round 4
// 442.724 us; speedup vs baseline: 1.3469x; 1.3469x over previous
//
#include <hip/hip_runtime.h>

// DenseGrid multi-LOD bilinear interpolation — binned, full-line-write pipeline.
// LODS = 16..2048, FEAT_DIM=4, N=2,000,000. Output [N,32] f32 (128B/point).
//
// R2: monolithic = L2-miss-latency bound on high-LOD gathers (FETCH 873MB).
// R3: binning fixed FETCH (77MB) but nt 16B scattered stores bypassed L2
//     write-combining (WRITE 277MB for 128MB dirty) -> scattered-write bound.
// R4: one thread per point computes ALL 8 LODs and writes the point's full
//     128B output line with 8 cached (non-nt) 16B stores -> L2 merges into a
//     fully-dirty line, clean writeback, no lowlod pass, no amplification.

typedef float    fx4 __attribute__((ext_vector_type(4)));
typedef float    fx2 __attribute__((ext_vector_type(2)));
typedef unsigned ux4 __attribute__((ext_vector_type(4)));

#define NBDIM 64
#define NBINS (NBDIM * NBDIM)

__device__ __forceinline__ fx4 bilerp_one(const float* __restrict__ g, int res,
                                          float px, float py) {
    float rm1 = (float)(res - 1);
    float fx = px * rm1, fy = py * rm1;
    float cmax = rm1 - 1e-5f;
    float xc = fminf(fmaxf(fx, 0.0f), cmax);
    float yc = fminf(fmaxf(fy, 0.0f), cmax);
    int x1 = (int)xc, y1 = (int)yc;              // xc,yc >= 0 -> trunc == floor
    int x2 = min(x1 + 1, res - 1), y2 = min(y1 + 1, res - 1);
    float x1f = (float)x1, y1f = (float)y1, x2f = (float)x2, y2f = (float)y2;
    float w1 = (x2f - fx) * (y2f - fy);
    float w2 = (fx - x1f) * (y2f - fy);
    float w3 = (x2f - fx) * (fy - y1f);
    float w4 = (fx - x1f) * (fy - y1f);
    const fx4* gc = (const fx4*)g;
    fx4 v1 = gc[x1 + y1 * res];
    fx4 v2 = gc[x2 + y1 * res];
    fx4 v3 = gc[x1 + y2 * res];
    fx4 v4 = gc[x2 + y2 * res];
    return w1 * v1 + w2 * v2 + w3 * v3 + w4 * v4;
}

__device__ __forceinline__ int bin_of(float px, float py) {
    int bx = min(max((int)(px * (float)NBDIM), 0), NBDIM - 1);
    int by = min(max((int)(py * (float)NBDIM), 0), NBDIM - 1);
    return by * NBDIM + bx;
}

// ---- Pass A1: histogram -----------------------------------------------------
__global__ __launch_bounds__(256) void hist_kernel(const float* __restrict__ x,
                                                   unsigned* __restrict__ hist,
                                                   int npts) {
    int n = blockIdx.x * 256 + threadIdx.x;
    if (n >= npts) return;
    fx2 p = *(const fx2*)(x + 2 * (size_t)n);
    atomicAdd(&hist[bin_of(p.x, p.y)], 1u);
}

// ---- Pass A2: exclusive scan of 4096 bins (single block) --------------------
__global__ __launch_bounds__(1024) void scan_kernel(const unsigned* __restrict__ hist,
                                                    unsigned* __restrict__ offs,
                                                    unsigned* __restrict__ starts,
                                                    int npts) {
    __shared__ unsigned s[1024];
    int t = threadIdx.x;
    ux4 h = ((const ux4*)hist)[t];               // 4 bins per thread
    unsigned seg = h.x + h.y + h.z + h.w;
    s[t] = seg;
    __syncthreads();
    for (int off = 1; off < 1024; off <<= 1) {   // Hillis-Steele inclusive
        unsigned v = (t >= off) ? s[t - off] : 0u;
        __syncthreads();
        s[t] += v;
        __syncthreads();
    }
    unsigned excl = t ? s[t - 1] : 0u;           // exclusive prefix of segment
    unsigned b0 = excl, b1 = b0 + h.x, b2 = b1 + h.y, b3 = b2 + h.z;
    offs[4 * t + 0] = b0;  starts[4 * t + 0] = b0;
    offs[4 * t + 1] = b1;  starts[4 * t + 1] = b1;
    offs[4 * t + 2] = b2;  starts[4 * t + 2] = b2;
    offs[4 * t + 3] = b3;  starts[4 * t + 3] = b3;
    if (t == 1023) starts[NBINS] = (unsigned)npts;
}

// ---- Pass A3: scatter records into bin order --------------------------------
__global__ __launch_bounds__(256) void scatter_kernel(const float* __restrict__ x,
                                                      unsigned* __restrict__ offs,
                                                      fx4* __restrict__ recs,
                                                      int npts) {
    int n = blockIdx.x * 256 + threadIdx.x;
    if (n >= npts) return;
    fx2 p = *(const fx2*)(x + 2 * (size_t)n);
    unsigned slot = atomicAdd(&offs[bin_of(p.x, p.y)], 1u);
    fx4 r;
    r.x = p.x; r.y = p.y; r.z = __uint_as_float((unsigned)n); r.w = 0.0f;
    recs[slot] = r;   // cached: slots within a bin are contiguous, L2 combines
}

// ---- Pass B: binned, ALL 8 LODs, one point per thread, full-line writes -----
__global__ __launch_bounds__(512) void binned_kernel(
    const fx4* __restrict__ recs, const unsigned* __restrict__ starts,
    const float* __restrict__ g0, const float* __restrict__ g1,
    const float* __restrict__ g2, const float* __restrict__ g3,
    const float* __restrict__ g4, const float* __restrict__ g5,
    const float* __restrict__ g6, const float* __restrict__ g7,
    float* __restrict__ out) {
    int b = blockIdx.x;
    unsigned s = starts[b], e = starts[b + 1];
    for (unsigned i = s + threadIdx.x; i < e; i += 512) {
        fx4 r = __builtin_nontemporal_load(&recs[i]);
        float px = r.x, py = r.y;
        unsigned n = __float_as_uint(r.z);
        fx4* op = (fx4*)out + (size_t)n * 8;
        // Cached stores: 8 consecutive 16B stores -> one fully-dirty 128B line.
        op[0] = bilerp_one(g0,   16, px, py);
        op[1] = bilerp_one(g1,   32, px, py);
        op[2] = bilerp_one(g2,   64, px, py);
        op[3] = bilerp_one(g3,  128, px, py);
        op[4] = bilerp_one(g4,  256, px, py);
        op[5] = bilerp_one(g5,  512, px, py);
        op[6] = bilerp_one(g6, 1024, px, py);
        op[7] = bilerp_one(g7, 2048, px, py);
    }
}

// ---- Fallback: proven round-2 monolithic kernel -----------------------------
__global__ __launch_bounds__(256) void densegrid_kernel(
    const float* __restrict__ xin,
    const float* __restrict__ g0, const float* __restrict__ g1,
    const float* __restrict__ g2, const float* __restrict__ g3,
    const float* __restrict__ g4, const float* __restrict__ g5,
    const float* __restrict__ g6, const float* __restrict__ g7,
    float* __restrict__ out, int npts) {
    int tid = blockIdx.x * blockDim.x + threadIdx.x;
    int n = tid >> 3;
    if (n >= npts) return;
    int lod = tid & 7;
    const float* g =
        (lod < 4) ? ((lod < 2) ? ((lod == 0) ? g0 : g1)
                               : ((lod == 2) ? g2 : g3))
                  : ((lod < 6) ? ((lod == 4) ? g4 : g5)
                               : ((lod == 6) ? g6 : g7));
    int res = 16 << lod;
    fx2 p = *(const fx2*)(xin + (size_t)n * 2);
    fx4 o = bilerp_one(g, res, p.x, p.y);
    __builtin_nontemporal_store(o, (fx4*)out + (size_t)n * 8 + lod);
}

extern "C" void kernel_launch(void* const* d_in, const int* in_sizes, int n_in,
                              void* d_out, int out_size, void* d_ws, size_t ws_size,
                              hipStream_t stream) {
    const float* x  = (const float*)d_in[0];
    const float* g0 = (const float*)d_in[1];
    const float* g1 = (const float*)d_in[2];
    const float* g2 = (const float*)d_in[3];
    const float* g3 = (const float*)d_in[4];
    const float* g4 = (const float*)d_in[5];
    const float* g5 = (const float*)d_in[6];
    const float* g6 = (const float*)d_in[7];
    const float* g7 = (const float*)d_in[8];
    float* out = (float*)d_out;
    int npts = in_sizes[0] / 2;

    // d_ws layout: hist @0 (16KB) | offs @16KB (16KB) | starts @32KB (16.4KB)
    //              | records @64KB (npts*16B)
    size_t need = 65536 + (size_t)npts * 16;
    if (ws_size >= need) {
        unsigned* hist   = (unsigned*)d_ws;
        unsigned* offs   = (unsigned*)((char*)d_ws + 16384);
        unsigned* starts = (unsigned*)((char*)d_ws + 32768);
        fx4*      recs   = (fx4*)((char*)d_ws + 65536);

        hipMemsetAsync(hist, 0, NBINS * sizeof(unsigned), stream);

        int gpts = (npts + 255) / 256;
        hist_kernel<<<gpts, 256, 0, stream>>>(x, hist, npts);
        scan_kernel<<<1, 1024, 0, stream>>>(hist, offs, starts, npts);
        scatter_kernel<<<gpts, 256, 0, stream>>>(x, offs, recs, npts);
        binned_kernel<<<NBINS, 512, 0, stream>>>(recs, starts,
                                                 g0, g1, g2, g3, g4, g5, g6, g7,
                                                 out);
    } else {
        int total = npts * 8;
        densegrid_kernel<<<(total + 255) / 256, 256, 0, stream>>>(
            x, g0, g1, g2, g3, g4, g5, g6, g7, out, npts);
    }
}

// Round 5
// 406.189 us; speedup vs baseline: 1.4680x; 1.0899x over previous
//
#include <hip/hip_runtime.h>

// DenseGrid multi-LOD bilinear — binned pipeline v3.
// R2: monolithic = L2-miss-latency bound (FETCH 873MB, 340us).
// R3: binning fixed FETCH; nt scattered stores broke write-combining (596us).
// R4: full-line cached writes; binned 167us but pre-pass atomics ~275us and
//     binned is TA-transaction bound (~40 divergent lines/point).
// R5: (1) 8 replica counters per bin -> atomic contention /8;
//     (2) 4B records (index only), binned re-reads x[n];
//     (3) LDS-staged LOD4..7 tiles per bin -> divergent gathers become LDS reads.

typedef float    fx4 __attribute__((ext_vector_type(4)));
typedef float    fx2 __attribute__((ext_vector_type(2)));
typedef unsigned ux4 __attribute__((ext_vector_type(4)));

#define NBDIM 64
#define NBINS (NBDIM * NBDIM)
#define NREP  8
#define NCNT  (NBINS * NREP)

__device__ __forceinline__ int bin_of(float px, float py) {
    int bx = min(max((int)(px * (float)NBDIM), 0), NBDIM - 1);
    int by = min(max((int)(py * (float)NBDIM), 0), NBDIM - 1);
    return by * NBDIM + bx;
}

__device__ __forceinline__ fx4 bilerp_one(const float* __restrict__ g, int res,
                                          float px, float py) {
    float rm1 = (float)(res - 1);
    float fx = px * rm1, fy = py * rm1;
    float cmax = rm1 - 1e-5f;
    float xc = fminf(fmaxf(fx, 0.0f), cmax);
    float yc = fminf(fmaxf(fy, 0.0f), cmax);
    int x1 = (int)xc, y1 = (int)yc;              // >=0 -> trunc == floor
    int x2 = min(x1 + 1, res - 1), y2 = min(y1 + 1, res - 1);
    float x1f = (float)x1, y1f = (float)y1, x2f = (float)x2, y2f = (float)y2;
    float w1 = (x2f - fx) * (y2f - fy);
    float w2 = (fx - x1f) * (y2f - fy);
    float w3 = (x2f - fx) * (fy - y1f);
    float w4 = (fx - x1f) * (fy - y1f);
    const fx4* gc = (const fx4*)g;
    fx4 v1 = gc[x1 + y1 * res];
    fx4 v2 = gc[x2 + y1 * res];
    fx4 v3 = gc[x1 + y2 * res];
    fx4 v4 = gc[x2 + y2 * res];
    return w1 * v1 + w2 * v2 + w3 * v3 + w4 * v4;
}

// LDS tile variants: same math, reads from staged tile (origin tx0,ty0).
template<int R, int STRIDE>
__device__ __forceinline__ fx4 bilerp_tile(const fx4* __restrict__ t,
                                           int tx0, int ty0, float px, float py) {
    float rm1 = (float)(R - 1);
    float fx = px * rm1, fy = py * rm1;
    float cmax = rm1 - 1e-5f;
    float xc = fminf(fmaxf(fx, 0.0f), cmax);
    float yc = fminf(fmaxf(fy, 0.0f), cmax);
    int x1 = (int)xc, y1 = (int)yc;
    int x2 = min(x1 + 1, R - 1), y2 = min(y1 + 1, R - 1);
    float x1f = (float)x1, y1f = (float)y1, x2f = (float)x2, y2f = (float)y2;
    float w1 = (x2f - fx) * (y2f - fy);
    float w2 = (fx - x1f) * (y2f - fy);
    float w3 = (x2f - fx) * (fy - y1f);
    float w4 = (fx - x1f) * (fy - y1f);
    int lx1 = x1 - tx0, ly1 = y1 - ty0;
    int lx2 = x2 - tx0, ly2 = y2 - ty0;
    fx4 v1 = t[ly1 * STRIDE + lx1];
    fx4 v2 = t[ly1 * STRIDE + lx2];
    fx4 v3 = t[ly2 * STRIDE + lx1];
    fx4 v4 = t[ly2 * STRIDE + lx2];
    return w1 * v1 + w2 * v2 + w3 * v3 + w4 * v4;
}

template<int R, int W, int STRIDE>
__device__ __forceinline__ void stage_tile(const fx4* __restrict__ gc,
                                           int tx0, int ty0, fx4* t, int tid) {
    for (int i = tid; i < W * W; i += 512) {
        int row = i / W, col = i - row * W;
        int gx = min(tx0 + col, R - 1);
        int gy = min(ty0 + row, R - 1);
        t[row * STRIDE + col] = gc[gy * R + gx];
    }
}

// ---- Pass A1: replicated histogram (2 points/thread) ------------------------
__global__ __launch_bounds__(256) void hist_kernel(const float* __restrict__ x,
                                                   unsigned* __restrict__ hist,
                                                   int npts) {
    int t = blockIdx.x * 256 + threadIdx.x;
    int n0 = t * 2;
    if (n0 >= npts) return;
    int r = threadIdx.x & (NREP - 1);
    fx4 p2 = *(const fx4*)(x + 2 * (size_t)n0);       // points n0, n0+1
    atomicAdd(&hist[bin_of(p2.x, p2.y) * NREP + r], 1u);
    if (n0 + 1 < npts)
        atomicAdd(&hist[bin_of(p2.z, p2.w) * NREP + r], 1u);
}

// ---- Pass A2: scan 32768 counters (bin-major, replica-minor) ----------------
__global__ __launch_bounds__(1024) void scan_kernel(const unsigned* __restrict__ hist,
                                                    unsigned* __restrict__ offs,
                                                    unsigned* __restrict__ starts,
                                                    int npts) {
    __shared__ unsigned s[1024];
    int t = threadIdx.x;
    unsigned h[32];
    #pragma unroll
    for (int j = 0; j < 8; ++j) {
        ux4 v = ((const ux4*)hist)[t * 8 + j];
        h[4 * j + 0] = v.x; h[4 * j + 1] = v.y;
        h[4 * j + 2] = v.z; h[4 * j + 3] = v.w;
    }
    unsigned seg = 0;
    #pragma unroll
    for (int j = 0; j < 32; ++j) seg += h[j];
    s[t] = seg;
    __syncthreads();
    for (int off = 1; off < 1024; off <<= 1) {        // Hillis-Steele inclusive
        unsigned v = (t >= off) ? s[t - off] : 0u;
        __syncthreads();
        s[t] += v;
        __syncthreads();
    }
    unsigned run = t ? s[t - 1] : 0u;
    #pragma unroll
    for (int j = 0; j < 32; ++j) {
        if ((j & 7) == 0) starts[t * 4 + (j >> 3)] = run;   // bin boundary
        offs[t * 32 + j] = run;
        run += h[j];
    }
    if (t == 1023) starts[NBINS] = (unsigned)npts;
}

// ---- Pass A3: scatter point INDICES into bin order --------------------------
__global__ __launch_bounds__(256) void scatter_kernel(const float* __restrict__ x,
                                                      unsigned* __restrict__ offs,
                                                      unsigned* __restrict__ recs,
                                                      int npts) {
    int t = blockIdx.x * 256 + threadIdx.x;
    int n0 = t * 2;
    if (n0 >= npts) return;
    int r = threadIdx.x & (NREP - 1);
    fx4 p2 = *(const fx4*)(x + 2 * (size_t)n0);
    unsigned s0 = atomicAdd(&offs[bin_of(p2.x, p2.y) * NREP + r], 1u);
    recs[s0] = (unsigned)n0;
    if (n0 + 1 < npts) {
        unsigned s1 = atomicAdd(&offs[bin_of(p2.z, p2.w) * NREP + r], 1u);
        recs[s1] = (unsigned)(n0 + 1);
    }
}

// ---- Pass B: one bin per block, LDS-staged LOD4..7, full-line writes --------
__global__ __launch_bounds__(512) void binned_kernel(
    const unsigned* __restrict__ recs, const unsigned* __restrict__ starts,
    const float* __restrict__ x,
    const float* __restrict__ g0, const float* __restrict__ g1,
    const float* __restrict__ g2, const float* __restrict__ g3,
    const float* __restrict__ g4, const float* __restrict__ g5,
    const float* __restrict__ g6, const float* __restrict__ g7,
    float* __restrict__ out) {
    __shared__ fx4 t7[34 * 35];
    __shared__ fx4 t6[18 * 19];
    __shared__ fx4 t5[10 * 11];
    __shared__ fx4 t4[6 * 7];
    int b = blockIdx.x;
    int bx = b & (NBDIM - 1), by = b >> 6;
    int tid = threadIdx.x;
    int tx7 = (bx * 2047) >> 6, ty7 = (by * 2047) >> 6;
    int tx6 = (bx * 1023) >> 6, ty6 = (by * 1023) >> 6;
    int tx5 = (bx *  511) >> 6, ty5 = (by *  511) >> 6;
    int tx4 = (bx *  255) >> 6, ty4 = (by *  255) >> 6;
    stage_tile<2048, 34, 35>((const fx4*)g7, tx7, ty7, t7, tid);
    stage_tile<1024, 18, 19>((const fx4*)g6, tx6, ty6, t6, tid);
    stage_tile< 512, 10, 11>((const fx4*)g5, tx5, ty5, t5, tid);
    stage_tile< 256,  6,  7>((const fx4*)g4, tx4, ty4, t4, tid);
    __syncthreads();
    unsigned s = starts[b], e = starts[b + 1];
    for (unsigned i = s + tid; i < e; i += 512) {
        unsigned n = __builtin_nontemporal_load(&recs[i]);
        fx2 p = *(const fx2*)(x + 2 * (size_t)n);
        fx4* op = (fx4*)out + (size_t)n * 8;
        // 8 consecutive cached 16B stores -> one fully-dirty 128B line.
        op[0] = bilerp_one(g0,  16, p.x, p.y);
        op[1] = bilerp_one(g1,  32, p.x, p.y);
        op[2] = bilerp_one(g2,  64, p.x, p.y);
        op[3] = bilerp_one(g3, 128, p.x, p.y);
        op[4] = bilerp_tile< 256,  7>(t4, tx4, ty4, p.x, p.y);
        op[5] = bilerp_tile< 512, 11>(t5, tx5, ty5, p.x, p.y);
        op[6] = bilerp_tile<1024, 19>(t6, tx6, ty6, p.x, p.y);
        op[7] = bilerp_tile<2048, 35>(t7, tx7, ty7, p.x, p.y);
    }
}

// ---- Fallback: proven round-2 monolithic kernel -----------------------------
__global__ __launch_bounds__(256) void densegrid_kernel(
    const float* __restrict__ xin,
    const float* __restrict__ g0, const float* __restrict__ g1,
    const float* __restrict__ g2, const float* __restrict__ g3,
    const float* __restrict__ g4, const float* __restrict__ g5,
    const float* __restrict__ g6, const float* __restrict__ g7,
    float* __restrict__ out, int npts) {
    int tid = blockIdx.x * blockDim.x + threadIdx.x;
    int n = tid >> 3;
    if (n >= npts) return;
    int lod = tid & 7;
    const float* g =
        (lod < 4) ? ((lod < 2) ? ((lod == 0) ? g0 : g1)
                               : ((lod == 2) ? g2 : g3))
                  : ((lod < 6) ? ((lod == 4) ? g4 : g5)
                               : ((lod == 6) ? g6 : g7));
    int res = 16 << lod;
    fx2 p = *(const fx2*)(xin + (size_t)n * 2);
    fx4 o = bilerp_one(g, res, p.x, p.y);
    __builtin_nontemporal_store(o, (fx4*)out + (size_t)n * 8 + lod);
}

extern "C" void kernel_launch(void* const* d_in, const int* in_sizes, int n_in,
                              void* d_out, int out_size, void* d_ws, size_t ws_size,
                              hipStream_t stream) {
    const float* x  = (const float*)d_in[0];
    const float* g0 = (const float*)d_in[1];
    const float* g1 = (const float*)d_in[2];
    const float* g2 = (const float*)d_in[3];
    const float* g3 = (const float*)d_in[4];
    const float* g4 = (const float*)d_in[5];
    const float* g5 = (const float*)d_in[6];
    const float* g6 = (const float*)d_in[7];
    const float* g7 = (const float*)d_in[8];
    float* out = (float*)d_out;
    int npts = in_sizes[0] / 2;

    // ws: hist @0 (128KB) | offs @128K (128KB) | starts @256K (16.4KB, pad 32K)
    //     | recs(u32) @288K (npts*4B)
    size_t need = 294912 + (size_t)npts * 4;
    if (ws_size >= need) {
        unsigned* hist   = (unsigned*)d_ws;
        unsigned* offs   = (unsigned*)((char*)d_ws + 131072);
        unsigned* starts = (unsigned*)((char*)d_ws + 262144);
        unsigned* recs   = (unsigned*)((char*)d_ws + 294912);

        hipMemsetAsync(hist, 0, NCNT * sizeof(unsigned), stream);

        int gpair = ((npts + 1) / 2 + 255) / 256;
        hist_kernel<<<gpair, 256, 0, stream>>>(x, hist, npts);
        scan_kernel<<<1, 1024, 0, stream>>>(hist, offs, starts, npts);
        scatter_kernel<<<gpair, 256, 0, stream>>>(x, offs, recs, npts);
        binned_kernel<<<NBINS, 512, 0, stream>>>(recs, starts, x,
                                                 g0, g1, g2, g3, g4, g5, g6, g7,
                                                 out);
    } else {
        int total = npts * 8;
        densegrid_kernel<<<(total + 255) / 256, 256, 0, stream>>>(
            x, g0, g1, g2, g3, g4, g5, g6, g7, out, npts);
    }
}

// Round 6
// 228.556 us; speedup vs baseline: 2.6089x; 1.7772x over previous
//
#include <hip/hip_runtime.h>

// DenseGrid multi-LOD bilinear — binned pipeline v4 (atomic-free sort).
// R2: monolithic 340us, L2-miss-latency bound (FETCH 873MB).
// R3/R4: binning fixed FETCH; full-line cached writes fixed WRITE; binned 167us
//        but pre-pass GLOBAL atomics ~235-275us (device-scope throughput bound
//        across 8 XCDs — 8x replication didn't help).
// R5: LDS tile staging: no gain (FETCH up, bank conflicts, same time).
// R6: (1) atomic-free counting sort: block-LDS hist -> cnt[bin][blk] matrix ->
//         rowsum -> scan -> rowscan -> scatter with LDS-local ranks;
//     (2) binned pass uses 8-lanes-per-point (lane=LOD): one store instr per
//         wave writes 8 full 128B lines; 4B records; XCD-swizzled bins.

typedef float    fx4 __attribute__((ext_vector_type(4)));
typedef float    fx2 __attribute__((ext_vector_type(2)));
typedef unsigned ux4 __attribute__((ext_vector_type(4)));

#define NBDIM 64
#define NBINS (NBDIM * NBDIM)
#define PPB   8192              // points per block in hist/scatter

__device__ __forceinline__ int bin_of(float px, float py) {
    int bx = min(max((int)(px * (float)NBDIM), 0), NBDIM - 1);
    int by = min(max((int)(py * (float)NBDIM), 0), NBDIM - 1);
    return by * NBDIM + bx;
}

__device__ __forceinline__ fx4 bilerp_one(const float* __restrict__ g, int res,
                                          float px, float py) {
    float rm1 = (float)(res - 1);
    float fx = px * rm1, fy = py * rm1;
    float cmax = rm1 - 1e-5f;
    float xc = fminf(fmaxf(fx, 0.0f), cmax);
    float yc = fminf(fmaxf(fy, 0.0f), cmax);
    int x1 = (int)xc, y1 = (int)yc;              // >=0 -> trunc == floor
    int x2 = min(x1 + 1, res - 1), y2 = min(y1 + 1, res - 1);
    float x1f = (float)x1, y1f = (float)y1, x2f = (float)x2, y2f = (float)y2;
    float w1 = (x2f - fx) * (y2f - fy);
    float w2 = (fx - x1f) * (y2f - fy);
    float w3 = (x2f - fx) * (fy - y1f);
    float w4 = (fx - x1f) * (fy - y1f);
    const fx4* gc = (const fx4*)g;
    fx4 v1 = gc[x1 + y1 * res];
    fx4 v2 = gc[x2 + y1 * res];
    fx4 v3 = gc[x1 + y2 * res];
    fx4 v4 = gc[x2 + y2 * res];
    return w1 * v1 + w2 * v2 + w3 * v3 + w4 * v4;
}

// ---- P1: per-block LDS histogram -> cnt[bin*nblk + blk] ---------------------
__global__ __launch_bounds__(1024) void hist2_kernel(const float* __restrict__ x,
                                                     unsigned* __restrict__ cnt,
                                                     int npts, int nblk) {
    __shared__ unsigned h[NBINS];                 // 16 KB
    int t = threadIdx.x, blk = blockIdx.x;
    for (int i = t; i < NBINS; i += 1024) h[i] = 0;
    __syncthreads();
    size_t base = (size_t)blk * PPB;
    #pragma unroll
    for (int j = 0; j < 4; ++j) {
        size_t n = base + (size_t)j * 2048 + (size_t)t * 2;  // 2 pts/thread/iter
        if (n < (size_t)npts) {
            if (n + 1 < (size_t)npts) {
                fx4 q = *(const fx4*)(x + 2 * n);
                atomicAdd(&h[bin_of(q.x, q.y)], 1u);
                atomicAdd(&h[bin_of(q.z, q.w)], 1u);
            } else {
                fx2 q = *(const fx2*)(x + 2 * n);
                atomicAdd(&h[bin_of(q.x, q.y)], 1u);
            }
        }
    }
    __syncthreads();
    for (int i = t; i < NBINS; i += 1024)
        cnt[(size_t)i * nblk + blk] = h[i];
}

// ---- P2: per-bin totals (one wave per bin row) ------------------------------
__global__ __launch_bounds__(256) void rowsum_kernel(const unsigned* __restrict__ cnt,
                                                     unsigned* __restrict__ T,
                                                     int nblk) {
    int wave = (blockIdx.x * 256 + threadIdx.x) >> 6;
    int lane = threadIdx.x & 63;
    if (wave >= NBINS) return;
    const unsigned* row = cnt + (size_t)wave * nblk;
    unsigned sum = 0;
    for (int c = lane; c < nblk; c += 64) sum += row[c];
    #pragma unroll
    for (int d = 32; d; d >>= 1) sum += __shfl_down(sum, d, 64);
    if (lane == 0) T[wave] = sum;
}

// ---- P3: exclusive scan of 4096 bin totals (single block) -------------------
__global__ __launch_bounds__(1024) void scanT_kernel(const unsigned* __restrict__ T,
                                                     unsigned* __restrict__ binStart,
                                                     int npts) {
    __shared__ unsigned s[1024];
    int t = threadIdx.x;
    ux4 h = ((const ux4*)T)[t];
    unsigned seg = h.x + h.y + h.z + h.w;
    s[t] = seg;
    __syncthreads();
    for (int off = 1; off < 1024; off <<= 1) {    // Hillis-Steele inclusive
        unsigned v = (t >= off) ? s[t - off] : 0u;
        __syncthreads();
        s[t] += v;
        __syncthreads();
    }
    unsigned run = t ? s[t - 1] : 0u;
    binStart[4 * t + 0] = run; run += h.x;
    binStart[4 * t + 1] = run; run += h.y;
    binStart[4 * t + 2] = run; run += h.z;
    binStart[4 * t + 3] = run;
    if (t == 1023) binStart[NBINS] = (unsigned)npts;
}

// ---- P4: per-bin row exclusive scan + binStart -> offs[bin*nblk + blk] ------
__global__ __launch_bounds__(256) void rowscan_kernel(const unsigned* __restrict__ cnt,
                                                      const unsigned* __restrict__ binStart,
                                                      unsigned* __restrict__ offs,
                                                      int nblk) {
    int wave = (blockIdx.x * 256 + threadIdx.x) >> 6;
    int lane = threadIdx.x & 63;
    if (wave >= NBINS) return;
    const unsigned* row = cnt + (size_t)wave * nblk;
    unsigned* orow = offs + (size_t)wave * nblk;
    unsigned running = binStart[wave];
    for (int c0 = 0; c0 < nblk; c0 += 64) {
        int c = c0 + lane;
        unsigned v = (c < nblk) ? row[c] : 0u;
        unsigned orig = v;
        #pragma unroll
        for (int d = 1; d < 64; d <<= 1) {
            unsigned y = __shfl_up(v, d, 64);
            if (lane >= d) v += y;
        }
        if (c < nblk) orow[c] = running + v - orig;   // exclusive + base
        running += __shfl(v, 63, 64);
    }
}

// ---- P5: scatter point indices (LDS-local ranks, no global atomics) ---------
__global__ __launch_bounds__(1024) void scatter2_kernel(const float* __restrict__ x,
                                                        const unsigned* __restrict__ offs,
                                                        unsigned* __restrict__ recs,
                                                        int npts, int nblk) {
    __shared__ unsigned off[NBINS];               // 16 KB
    int t = threadIdx.x, blk = blockIdx.x;
    for (int i = t; i < NBINS; i += 1024)
        off[i] = offs[(size_t)i * nblk + blk];
    __syncthreads();
    size_t base = (size_t)blk * PPB;
    #pragma unroll
    for (int j = 0; j < 4; ++j) {
        size_t n = base + (size_t)j * 2048 + (size_t)t * 2;
        if (n < (size_t)npts) {
            if (n + 1 < (size_t)npts) {
                fx4 q = *(const fx4*)(x + 2 * n);
                unsigned s0 = atomicAdd(&off[bin_of(q.x, q.y)], 1u);
                unsigned s1 = atomicAdd(&off[bin_of(q.z, q.w)], 1u);
                recs[s0] = (unsigned)n;
                recs[s1] = (unsigned)(n + 1);
            } else {
                fx2 q = *(const fx2*)(x + 2 * n);
                unsigned s0 = atomicAdd(&off[bin_of(q.x, q.y)], 1u);
                recs[s0] = (unsigned)n;
            }
        }
    }
}

// ---- P6: binned main pass — 8 lanes per point (lane = LOD) ------------------
__global__ __launch_bounds__(512) void binned_kernel(
    const unsigned* __restrict__ recs, const unsigned* __restrict__ binStart,
    const float* __restrict__ x,
    const float* __restrict__ g0, const float* __restrict__ g1,
    const float* __restrict__ g2, const float* __restrict__ g3,
    const float* __restrict__ g4, const float* __restrict__ g5,
    const float* __restrict__ g6, const float* __restrict__ g7,
    float* __restrict__ out) {
    // XCD swizzle: 4096 bins % 8 == 0 -> each XCD gets 512 consecutive bins.
    int b = (blockIdx.x & 7) * (NBINS / 8) + (blockIdx.x >> 3);
    unsigned s = binStart[b], e = binStart[b + 1];
    int lod = threadIdx.x & 7;
    const float* g =
        (lod < 4) ? ((lod < 2) ? ((lod == 0) ? g0 : g1)
                               : ((lod == 2) ? g2 : g3))
                  : ((lod < 6) ? ((lod == 4) ? g4 : g5)
                               : ((lod == 6) ? g6 : g7));
    int res = 16 << lod;
    for (unsigned i = s + (threadIdx.x >> 3); i < e; i += 64) {
        unsigned n = __builtin_nontemporal_load(&recs[i]);  // 8 lanes share
        fx2 p = *(const fx2*)(x + 2 * (size_t)n);           // L3-resident
        fx4 o = bilerp_one(g, res, p.x, p.y);
        // lanes 8k..8k+7 write one fully-dirty contiguous 128B line
        ((fx4*)out)[(size_t)n * 8 + lod] = o;
    }
}

// ---- Fallback: proven round-2 monolithic kernel -----------------------------
__global__ __launch_bounds__(256) void densegrid_kernel(
    const float* __restrict__ xin,
    const float* __restrict__ g0, const float* __restrict__ g1,
    const float* __restrict__ g2, const float* __restrict__ g3,
    const float* __restrict__ g4, const float* __restrict__ g5,
    const float* __restrict__ g6, const float* __restrict__ g7,
    float* __restrict__ out, int npts) {
    int tid = blockIdx.x * blockDim.x + threadIdx.x;
    int n = tid >> 3;
    if (n >= npts) return;
    int lod = tid & 7;
    const float* g =
        (lod < 4) ? ((lod < 2) ? ((lod == 0) ? g0 : g1)
                               : ((lod == 2) ? g2 : g3))
                  : ((lod < 6) ? ((lod == 4) ? g4 : g5)
                               : ((lod == 6) ? g6 : g7));
    int res = 16 << lod;
    fx2 p = *(const fx2*)(xin + (size_t)n * 2);
    fx4 o = bilerp_one(g, res, p.x, p.y);
    __builtin_nontemporal_store(o, (fx4*)out + (size_t)n * 8 + lod);
}

extern "C" void kernel_launch(void* const* d_in, const int* in_sizes, int n_in,
                              void* d_out, int out_size, void* d_ws, size_t ws_size,
                              hipStream_t stream) {
    const float* x  = (const float*)d_in[0];
    const float* g0 = (const float*)d_in[1];
    const float* g1 = (const float*)d_in[2];
    const float* g2 = (const float*)d_in[3];
    const float* g3 = (const float*)d_in[4];
    const float* g4 = (const float*)d_in[5];
    const float* g5 = (const float*)d_in[6];
    const float* g6 = (const float*)d_in[7];
    const float* g7 = (const float*)d_in[8];
    float* out = (float*)d_out;
    int npts = in_sizes[0] / 2;

    int nblk = (npts + PPB - 1) / PPB;            // 245 for 2M points
    size_t mat = ((size_t)NBINS * nblk * 4 + 255) & ~(size_t)255;
    size_t o_cnt  = 0;
    size_t o_offs = o_cnt + mat;
    size_t o_T    = o_offs + mat;
    size_t o_bs   = o_T + ((NBINS * 4 + 255) & ~255);
    size_t o_recs = o_bs + (((NBINS + 1) * 4 + 255) & ~(size_t)255);
    size_t need   = o_recs + (size_t)npts * 4;

    if (ws_size >= need) {
        unsigned* cnt      = (unsigned*)((char*)d_ws + o_cnt);
        unsigned* offs     = (unsigned*)((char*)d_ws + o_offs);
        unsigned* T        = (unsigned*)((char*)d_ws + o_T);
        unsigned* binStart = (unsigned*)((char*)d_ws + o_bs);
        unsigned* recs     = (unsigned*)((char*)d_ws + o_recs);

        hist2_kernel<<<nblk, 1024, 0, stream>>>(x, cnt, npts, nblk);
        rowsum_kernel<<<(NBINS * 64) / 256, 256, 0, stream>>>(cnt, T, nblk);
        scanT_kernel<<<1, 1024, 0, stream>>>(T, binStart, npts);
        rowscan_kernel<<<(NBINS * 64) / 256, 256, 0, stream>>>(cnt, binStart, offs, nblk);
        scatter2_kernel<<<nblk, 1024, 0, stream>>>(x, offs, recs, npts, nblk);
        binned_kernel<<<NBINS, 512, 0, stream>>>(recs, binStart, x,
                                                 g0, g1, g2, g3, g4, g5, g6, g7,
                                                 out);
    } else {
        int total = npts * 8;
        densegrid_kernel<<<(total + 255) / 256, 256, 0, stream>>>(
            x, g0, g1, g2, g3, g4, g5, g6, g7, out, npts);
    }
}

// Round 7
// 223.987 us; speedup vs baseline: 2.6622x; 1.0204x over previous
//
#include <hip/hip_runtime.h>

// DenseGrid multi-LOD bilinear — binned pipeline v5.
// R2: monolithic 340us, L2-miss-latency bound (FETCH 873MB).
// R3/R4: binning fixed FETCH; full-line cached writes fixed WRITE.
// R5: LDS tile staging: null (FETCH up, bank conflicts).
// R6: atomic-free counting sort (pre-pass 235->35us) but 4B records forced
//     scattered x[n] re-reads: binned FETCH 82->215MB, 167->193us.
// R7: SoA coord records (recXY 8B + recN 4B = 12B/pt, ws 28.05MB < proven
//     32.07MB), nt full-line output stores (keep L2 for grids; pattern proven
//     amplification-free in R2), unroll-2 point loop, in-place rowscan.

typedef float    fx4 __attribute__((ext_vector_type(4)));
typedef float    fx2 __attribute__((ext_vector_type(2)));
typedef unsigned ux4 __attribute__((ext_vector_type(4)));

#define NBDIM 64
#define NBINS (NBDIM * NBDIM)
#define PPB   8192              // points per block in hist/scatter

__device__ __forceinline__ int bin_of(float px, float py) {
    int bx = min(max((int)(px * (float)NBDIM), 0), NBDIM - 1);
    int by = min(max((int)(py * (float)NBDIM), 0), NBDIM - 1);
    return by * NBDIM + bx;
}

__device__ __forceinline__ fx4 bilerp_one(const float* __restrict__ g, int res,
                                          float px, float py) {
    float rm1 = (float)(res - 1);
    float fx = px * rm1, fy = py * rm1;
    float cmax = rm1 - 1e-5f;
    float xc = fminf(fmaxf(fx, 0.0f), cmax);
    float yc = fminf(fmaxf(fy, 0.0f), cmax);
    int x1 = (int)xc, y1 = (int)yc;              // >=0 -> trunc == floor
    int x2 = min(x1 + 1, res - 1), y2 = min(y1 + 1, res - 1);
    float x1f = (float)x1, y1f = (float)y1, x2f = (float)x2, y2f = (float)y2;
    float w1 = (x2f - fx) * (y2f - fy);
    float w2 = (fx - x1f) * (y2f - fy);
    float w3 = (x2f - fx) * (fy - y1f);
    float w4 = (fx - x1f) * (fy - y1f);
    const fx4* gc = (const fx4*)g;
    fx4 v1 = gc[x1 + y1 * res];
    fx4 v2 = gc[x2 + y1 * res];
    fx4 v3 = gc[x1 + y2 * res];
    fx4 v4 = gc[x2 + y2 * res];
    return w1 * v1 + w2 * v2 + w3 * v3 + w4 * v4;
}

// ---- P1: per-block LDS histogram -> cnt[bin*nblk + blk] ---------------------
__global__ __launch_bounds__(1024) void hist2_kernel(const float* __restrict__ x,
                                                     unsigned* __restrict__ cnt,
                                                     int npts, int nblk) {
    __shared__ unsigned h[NBINS];                 // 16 KB
    int t = threadIdx.x, blk = blockIdx.x;
    for (int i = t; i < NBINS; i += 1024) h[i] = 0;
    __syncthreads();
    size_t base = (size_t)blk * PPB;
    #pragma unroll
    for (int j = 0; j < 4; ++j) {
        size_t n = base + (size_t)j * 2048 + (size_t)t * 2;  // 2 pts/thread/iter
        if (n < (size_t)npts) {
            if (n + 1 < (size_t)npts) {
                fx4 q = *(const fx4*)(x + 2 * n);
                atomicAdd(&h[bin_of(q.x, q.y)], 1u);
                atomicAdd(&h[bin_of(q.z, q.w)], 1u);
            } else {
                fx2 q = *(const fx2*)(x + 2 * n);
                atomicAdd(&h[bin_of(q.x, q.y)], 1u);
            }
        }
    }
    __syncthreads();
    for (int i = t; i < NBINS; i += 1024)
        cnt[(size_t)i * nblk + blk] = h[i];
}

// ---- P2: per-bin totals (one wave per bin row) ------------------------------
__global__ __launch_bounds__(256) void rowsum_kernel(const unsigned* __restrict__ cnt,
                                                     unsigned* __restrict__ T,
                                                     int nblk) {
    int wave = (blockIdx.x * 256 + threadIdx.x) >> 6;
    int lane = threadIdx.x & 63;
    if (wave >= NBINS) return;
    const unsigned* row = cnt + (size_t)wave * nblk;
    unsigned sum = 0;
    for (int c = lane; c < nblk; c += 64) sum += row[c];
    #pragma unroll
    for (int d = 32; d; d >>= 1) sum += __shfl_down(sum, d, 64);
    if (lane == 0) T[wave] = sum;
}

// ---- P3: exclusive scan of 4096 bin totals (single block) -------------------
__global__ __launch_bounds__(1024) void scanT_kernel(const unsigned* __restrict__ T,
                                                     unsigned* __restrict__ binStart,
                                                     int npts) {
    __shared__ unsigned s[1024];
    int t = threadIdx.x;
    ux4 h = ((const ux4*)T)[t];
    unsigned seg = h.x + h.y + h.z + h.w;
    s[t] = seg;
    __syncthreads();
    for (int off = 1; off < 1024; off <<= 1) {    // Hillis-Steele inclusive
        unsigned v = (t >= off) ? s[t - off] : 0u;
        __syncthreads();
        s[t] += v;
        __syncthreads();
    }
    unsigned run = t ? s[t - 1] : 0u;
    binStart[4 * t + 0] = run; run += h.x;
    binStart[4 * t + 1] = run; run += h.y;
    binStart[4 * t + 2] = run; run += h.z;
    binStart[4 * t + 3] = run;
    if (t == 1023) binStart[NBINS] = (unsigned)npts;
}

// ---- P4: per-bin row exclusive scan, IN PLACE (cnt becomes offs) ------------
__global__ __launch_bounds__(256) void rowscan_kernel(unsigned* __restrict__ cnt,
                                                      const unsigned* __restrict__ binStart,
                                                      int nblk) {
    int wave = (blockIdx.x * 256 + threadIdx.x) >> 6;
    int lane = threadIdx.x & 63;
    if (wave >= NBINS) return;
    unsigned* row = cnt + (size_t)wave * nblk;
    unsigned running = binStart[wave];
    for (int c0 = 0; c0 < nblk; c0 += 64) {
        int c = c0 + lane;
        unsigned v = (c < nblk) ? row[c] : 0u;
        unsigned orig = v;
        #pragma unroll
        for (int d = 1; d < 64; d <<= 1) {
            unsigned y = __shfl_up(v, d, 64);
            if (lane >= d) v += y;
        }
        if (c < nblk) row[c] = running + v - orig;    // exclusive + base
        running += __shfl(v, 63, 64);
    }
}

// ---- P5: scatter SoA records (LDS-local ranks, no global atomics) -----------
__global__ __launch_bounds__(1024) void scatter2_kernel(const float* __restrict__ x,
                                                        const unsigned* __restrict__ offs,
                                                        fx2* __restrict__ recXY,
                                                        unsigned* __restrict__ recN,
                                                        int npts, int nblk) {
    __shared__ unsigned off[NBINS];               // 16 KB
    int t = threadIdx.x, blk = blockIdx.x;
    for (int i = t; i < NBINS; i += 1024)
        off[i] = offs[(size_t)i * nblk + blk];
    __syncthreads();
    size_t base = (size_t)blk * PPB;
    #pragma unroll
    for (int j = 0; j < 4; ++j) {
        size_t n = base + (size_t)j * 2048 + (size_t)t * 2;
        if (n < (size_t)npts) {
            if (n + 1 < (size_t)npts) {
                fx4 q = *(const fx4*)(x + 2 * n);
                unsigned s0 = atomicAdd(&off[bin_of(q.x, q.y)], 1u);
                unsigned s1 = atomicAdd(&off[bin_of(q.z, q.w)], 1u);
                fx2 a; a.x = q.x; a.y = q.y;
                fx2 b2; b2.x = q.z; b2.y = q.w;
                recXY[s0] = a;  recN[s0] = (unsigned)n;
                recXY[s1] = b2; recN[s1] = (unsigned)(n + 1);
            } else {
                fx2 q = *(const fx2*)(x + 2 * n);
                unsigned s0 = atomicAdd(&off[bin_of(q.x, q.y)], 1u);
                recXY[s0] = q; recN[s0] = (unsigned)n;
            }
        }
    }
}

// ---- P6: binned main pass — 8 lanes per point (lane = LOD) ------------------
__global__ __launch_bounds__(512) void binned_kernel(
    const fx2* __restrict__ recXY, const unsigned* __restrict__ recN,
    const unsigned* __restrict__ binStart,
    const float* __restrict__ g0, const float* __restrict__ g1,
    const float* __restrict__ g2, const float* __restrict__ g3,
    const float* __restrict__ g4, const float* __restrict__ g5,
    const float* __restrict__ g6, const float* __restrict__ g7,
    float* __restrict__ out) {
    // XCD swizzle: 4096 bins % 8 == 0 -> each XCD gets 512 consecutive bins.
    int b = (blockIdx.x & 7) * (NBINS / 8) + (blockIdx.x >> 3);
    unsigned s = binStart[b], e = binStart[b + 1];
    int lod = threadIdx.x & 7;
    const float* g =
        (lod < 4) ? ((lod < 2) ? ((lod == 0) ? g0 : g1)
                               : ((lod == 2) ? g2 : g3))
                  : ((lod < 6) ? ((lod == 4) ? g4 : g5)
                               : ((lod == 6) ? g6 : g7));
    int res = 16 << lod;
    unsigned i = s + (threadIdx.x >> 3);
    // unroll-2: two independent rec->gather->store chains per thread
    for (; i + 64 < e; i += 128) {
        fx2 pa = __builtin_nontemporal_load(&recXY[i]);
        unsigned na = __builtin_nontemporal_load(&recN[i]);
        fx2 pb = __builtin_nontemporal_load(&recXY[i + 64]);
        unsigned nb = __builtin_nontemporal_load(&recN[i + 64]);
        fx4 oa = bilerp_one(g, res, pa.x, pa.y);
        fx4 ob = bilerp_one(g, res, pb.x, pb.y);
        __builtin_nontemporal_store(oa, (fx4*)out + (size_t)na * 8 + lod);
        __builtin_nontemporal_store(ob, (fx4*)out + (size_t)nb * 8 + lod);
    }
    for (; i < e; i += 64) {
        fx2 p = __builtin_nontemporal_load(&recXY[i]);
        unsigned n = __builtin_nontemporal_load(&recN[i]);
        fx4 o = bilerp_one(g, res, p.x, p.y);
        __builtin_nontemporal_store(o, (fx4*)out + (size_t)n * 8 + lod);
    }
}

// ---- Fallback: proven round-2 monolithic kernel -----------------------------
__global__ __launch_bounds__(256) void densegrid_kernel(
    const float* __restrict__ xin,
    const float* __restrict__ g0, const float* __restrict__ g1,
    const float* __restrict__ g2, const float* __restrict__ g3,
    const float* __restrict__ g4, const float* __restrict__ g5,
    const float* __restrict__ g6, const float* __restrict__ g7,
    float* __restrict__ out, int npts) {
    int tid = blockIdx.x * blockDim.x + threadIdx.x;
    int n = tid >> 3;
    if (n >= npts) return;
    int lod = tid & 7;
    const float* g =
        (lod < 4) ? ((lod < 2) ? ((lod == 0) ? g0 : g1)
                               : ((lod == 2) ? g2 : g3))
                  : ((lod < 6) ? ((lod == 4) ? g4 : g5)
                               : ((lod == 6) ? g6 : g7));
    int res = 16 << lod;
    fx2 p = *(const fx2*)(xin + (size_t)n * 2);
    fx4 o = bilerp_one(g, res, p.x, p.y);
    __builtin_nontemporal_store(o, (fx4*)out + (size_t)n * 8 + lod);
}

extern "C" void kernel_launch(void* const* d_in, const int* in_sizes, int n_in,
                              void* d_out, int out_size, void* d_ws, size_t ws_size,
                              hipStream_t stream) {
    const float* x  = (const float*)d_in[0];
    const float* g0 = (const float*)d_in[1];
    const float* g1 = (const float*)d_in[2];
    const float* g2 = (const float*)d_in[3];
    const float* g3 = (const float*)d_in[4];
    const float* g4 = (const float*)d_in[5];
    const float* g5 = (const float*)d_in[6];
    const float* g6 = (const float*)d_in[7];
    const float* g7 = (const float*)d_in[8];
    float* out = (float*)d_out;
    int npts = in_sizes[0] / 2;

    int nblk = (npts + PPB - 1) / PPB;            // 245 for 2M points
    size_t mat  = (((size_t)NBINS * nblk * 4) + 255) & ~(size_t)255;
    size_t o_T  = mat;
    size_t o_bs = o_T + (((size_t)NBINS * 4 + 255) & ~(size_t)255);
    size_t o_xy = o_bs + ((((size_t)NBINS + 1) * 4 + 255) & ~(size_t)255);
    size_t o_n  = o_xy + (size_t)npts * 8;
    size_t need = o_n + (size_t)npts * 4;         // ~28.05 MB @ 2M pts

    if (ws_size >= need) {
        unsigned* cnt      = (unsigned*)d_ws;     // becomes offs after rowscan
        unsigned* T        = (unsigned*)((char*)d_ws + o_T);
        unsigned* binStart = (unsigned*)((char*)d_ws + o_bs);
        fx2*      recXY    = (fx2*)((char*)d_ws + o_xy);
        unsigned* recN     = (unsigned*)((char*)d_ws + o_n);

        hist2_kernel<<<nblk, 1024, 0, stream>>>(x, cnt, npts, nblk);
        rowsum_kernel<<<(NBINS * 64) / 256, 256, 0, stream>>>(cnt, T, nblk);
        scanT_kernel<<<1, 1024, 0, stream>>>(T, binStart, npts);
        rowscan_kernel<<<(NBINS * 64) / 256, 256, 0, stream>>>(cnt, binStart, nblk);
        scatter2_kernel<<<nblk, 1024, 0, stream>>>(x, cnt, recXY, recN, npts, nblk);
        binned_kernel<<<NBINS, 512, 0, stream>>>(recXY, recN, binStart,
                                                 g0, g1, g2, g3, g4, g5, g6, g7,
                                                 out);
    } else {
        int total = npts * 8;
        densegrid_kernel<<<(total + 255) / 256, 256, 0, stream>>>(
            x, g0, g1, g2, g3, g4, g5, g6, g7, out, npts);
    }
}